// Round 3
// baseline (1757.627 us; speedup 1.0000x reference)
//
#include <hip/hip_runtime.h>

#define NN 20000
#define NE 400000
#define CC 128
#define HH 8
#define DD 16
#define BBg 32
#define NC (NN * CC)      // 2,560,000
#define NHt (NN * HH)     // 160,000

typedef __attribute__((ext_vector_type(8))) short short8;
typedef __attribute__((ext_vector_type(4))) float floatx4;

__device__ inline unsigned short bf16_trunc(float f) {
    return (unsigned short)(__float_as_uint(f) >> 16);
}

// ===========================================================================
// CSR build (once per call, per edge type)
// ===========================================================================
__global__ __launch_bounds__(256) void hist_kernel(const int* __restrict__ ei,
                                                   int* __restrict__ deg)
{
    const int e = blockIdx.x * 256 + threadIdx.x;
    if (e >= NE) return;
    atomicAdd(&deg[ei[NE + e]], 1);
}

__global__ __launch_bounds__(1024) void scan_kernel(const int* __restrict__ deg,
                                                    int* __restrict__ rowptr,
                                                    int* __restrict__ cursor)
{
    __shared__ int part[1024];
    const int tid = threadIdx.x;
    const int base = tid * 20;
    int s = 0;
    for (int k = 0; k < 20; k++) { int i = base + k; if (i < NN) s += deg[i]; }
    part[tid] = s;
    __syncthreads();
    if (tid == 0) {
        int run = 0;
        for (int i = 0; i < 1024; i++) { int t = part[i]; part[i] = run; run += t; }
        rowptr[NN] = run;
    }
    __syncthreads();
    int run = part[tid];
    for (int k = 0; k < 20; k++) {
        int i = base + k;
        if (i < NN) { rowptr[i] = run; cursor[i] = run; run += deg[i]; }
    }
}

__global__ __launch_bounds__(256) void scatter_kernel(const int* __restrict__ ei,
                                                      int* __restrict__ cursor,
                                                      int* __restrict__ srcs)
{
    const int e = blockIdx.x * 256 + threadIdx.x;
    if (e >= NE) return;
    const int pos = atomicAdd(&cursor[ei[NE + e]], 1);
    srcs[pos] = ei[e];
}

// ===========================================================================
// W prep: 9 mats fp32 [k][n] -> transposed bf16 hi/lo [n][k] (split-float)
// mats 0..5 = proj_w[l][t], 6..8 = k_w[l]
// ===========================================================================
__global__ __launch_bounds__(256) void wprep_kernel(
    const float* __restrict__ proj_w, const float* __restrict__ k_w,
    unsigned short* __restrict__ wt_hi, unsigned short* __restrict__ wt_lo)
{
    const int idx = blockIdx.x * 256 + threadIdx.x;   // mat*16384 + n*128 + k
    if (idx >= 9 * 16384) return;
    const int mat = idx >> 14, r = idx & 16383;
    const int n = r >> 7, k = r & 127;
    const float* W = (mat < 6) ? (proj_w + (size_t)mat * 16384)
                               : (k_w + (size_t)(mat - 6) * 16384);
    float f = W[k * 128 + n];
    unsigned short hi = bf16_trunc(f);
    float fh = __uint_as_float((unsigned)hi << 16);
    wt_hi[idx] = hi;
    wt_lo[idx] = bf16_trunc(f - fh);
}

// ===========================================================================
// MFMA GEMM core macro pieces (M=128/block, N=128, K=128; 4 waves x 32 rows)
// A layout: m=lane&15, k=quad*8+j ; B: n=lane&15, k=quad*8+j ; D: m=quad*4+r, n=lane&15
// ===========================================================================
__global__ __launch_bounds__(256) void proj_mfma(
    const float* __restrict__ X0, const float* __restrict__ X1,
    const unsigned short* __restrict__ whi_l, const unsigned short* __restrict__ wlo_l,
    const float* __restrict__ bias_l,
    float* __restrict__ Y0, float* __restrict__ Y1)
{
    const int t = blockIdx.y;
    const float* X = t ? X1 : X0;
    const unsigned short* whi = whi_l + (size_t)t * 16384;
    const unsigned short* wlo = wlo_l + (size_t)t * 16384;
    const float* bias = bias_l + t * CC;
    float* Y = t ? Y1 : Y0;

    __shared__ unsigned short Bh[128 * 136];
    __shared__ unsigned short Bl[128 * 136];
    const int tid = threadIdx.x;
    for (int i = tid; i < 128 * 16; i += 256) {
        int n = i >> 4, ch = (i & 15) * 8;
        *(short8*)&Bh[n * 136 + ch] = *(const short8*)&whi[n * 128 + ch];
        *(short8*)&Bl[n * 136 + ch] = *(const short8*)&wlo[n * 128 + ch];
    }
    __syncthreads();

    const int wave = tid >> 6, lane = tid & 63;
    const int ln = lane & 15, quad = lane >> 4;
    const int rW = blockIdx.x * 128 + wave * 32;

    floatx4 acc[2][8];
#pragma unroll
    for (int mh = 0; mh < 2; mh++)
#pragma unroll
        for (int nt = 0; nt < 8; nt++) acc[mh][nt] = (floatx4){0.f, 0.f, 0.f, 0.f};

    for (int ki = 0; ki < 4; ki++) {
        short8 ahi[2], alo[2];
#pragma unroll
        for (int mh = 0; mh < 2; mh++) {
            int row = rW + mh * 16 + ln; if (row > NN - 1) row = NN - 1;
            const float* ap = X + (size_t)row * CC + ki * 32 + quad * 8;
            float4 a0 = *(const float4*)ap;
            float4 a1 = *(const float4*)(ap + 4);
            float av[8] = {a0.x, a0.y, a0.z, a0.w, a1.x, a1.y, a1.z, a1.w};
#pragma unroll
            for (int j = 0; j < 8; j++) {
                unsigned short h = bf16_trunc(av[j]);
                float fh = __uint_as_float((unsigned)h << 16);
                ahi[mh][j] = (short)h;
                alo[mh][j] = (short)bf16_trunc(av[j] - fh);
            }
        }
        const int kb = ki * 32 + quad * 8;
#pragma unroll
        for (int nt = 0; nt < 8; nt++) {
            short8 bh = *(const short8*)&Bh[(nt * 16 + ln) * 136 + kb];
            short8 bl = *(const short8*)&Bl[(nt * 16 + ln) * 136 + kb];
#pragma unroll
            for (int mh = 0; mh < 2; mh++) {
                acc[mh][nt] = __builtin_amdgcn_mfma_f32_16x16x32_bf16(ahi[mh], bh, acc[mh][nt], 0, 0, 0);
                acc[mh][nt] = __builtin_amdgcn_mfma_f32_16x16x32_bf16(alo[mh], bh, acc[mh][nt], 0, 0, 0);
                acc[mh][nt] = __builtin_amdgcn_mfma_f32_16x16x32_bf16(ahi[mh], bl, acc[mh][nt], 0, 0, 0);
            }
        }
    }
#pragma unroll
    for (int mh = 0; mh < 2; mh++)
#pragma unroll
        for (int nt = 0; nt < 8; nt++) {
            float bv = bias[nt * 16 + ln];
#pragma unroll
            for (int r = 0; r < 4; r++) {
                int row = rW + mh * 16 + quad * 4 + r;
                if (row < NN) Y[(size_t)row * CC + nt * 16 + ln] = acc[mh][nt][r] + bv;
            }
        }
}

__global__ __launch_bounds__(256) void semcol_mfma(
    const float* __restrict__ Obase,
    const unsigned short* __restrict__ whi, const unsigned short* __restrict__ wlo,
    const float* __restrict__ Kb, float* __restrict__ colsum)
{
    const int s = blockIdx.y;
    const float* X = Obase + (size_t)s * NC;

    __shared__ unsigned short Bh[128 * 136];
    __shared__ unsigned short Bl[128 * 136];
    __shared__ float red[4 * 128];
    const int tid = threadIdx.x;
    for (int i = tid; i < 128 * 16; i += 256) {
        int n = i >> 4, ch = (i & 15) * 8;
        *(short8*)&Bh[n * 136 + ch] = *(const short8*)&whi[n * 128 + ch];
        *(short8*)&Bl[n * 136 + ch] = *(const short8*)&wlo[n * 128 + ch];
    }
    __syncthreads();

    const int wave = tid >> 6, lane = tid & 63;
    const int ln = lane & 15, quad = lane >> 4;
    const int rW = blockIdx.x * 128 + wave * 32;

    floatx4 acc[2][8];
#pragma unroll
    for (int mh = 0; mh < 2; mh++)
#pragma unroll
        for (int nt = 0; nt < 8; nt++) acc[mh][nt] = (floatx4){0.f, 0.f, 0.f, 0.f};

    for (int ki = 0; ki < 4; ki++) {
        short8 ahi[2], alo[2];
#pragma unroll
        for (int mh = 0; mh < 2; mh++) {
            int row = rW + mh * 16 + ln; if (row > NN - 1) row = NN - 1;
            const float* ap = X + (size_t)row * CC + ki * 32 + quad * 8;
            float4 a0 = *(const float4*)ap;
            float4 a1 = *(const float4*)(ap + 4);
            float av[8] = {a0.x, a0.y, a0.z, a0.w, a1.x, a1.y, a1.z, a1.w};
#pragma unroll
            for (int j = 0; j < 8; j++) {
                unsigned short h = bf16_trunc(av[j]);
                float fh = __uint_as_float((unsigned)h << 16);
                ahi[mh][j] = (short)h;
                alo[mh][j] = (short)bf16_trunc(av[j] - fh);
            }
        }
        const int kb = ki * 32 + quad * 8;
#pragma unroll
        for (int nt = 0; nt < 8; nt++) {
            short8 bh = *(const short8*)&Bh[(nt * 16 + ln) * 136 + kb];
            short8 bl = *(const short8*)&Bl[(nt * 16 + ln) * 136 + kb];
#pragma unroll
            for (int mh = 0; mh < 2; mh++) {
                acc[mh][nt] = __builtin_amdgcn_mfma_f32_16x16x32_bf16(ahi[mh], bh, acc[mh][nt], 0, 0, 0);
                acc[mh][nt] = __builtin_amdgcn_mfma_f32_16x16x32_bf16(alo[mh], bh, acc[mh][nt], 0, 0, 0);
                acc[mh][nt] = __builtin_amdgcn_mfma_f32_16x16x32_bf16(ahi[mh], bl, acc[mh][nt], 0, 0, 0);
            }
        }
    }
    // epilogue: colsum[s][c] += sum_rows tanh(acc + Kb[c])
    float tsum[8];
#pragma unroll
    for (int nt = 0; nt < 8; nt++) {
        float bv = Kb[nt * 16 + ln];
        float v = 0.f;
#pragma unroll
        for (int mh = 0; mh < 2; mh++)
#pragma unroll
            for (int r = 0; r < 4; r++) {
                int row = rW + mh * 16 + quad * 4 + r;
                if (row < NN) v += tanhf(acc[mh][nt][r] + bv);
            }
        v += __shfl_xor(v, 16);
        v += __shfl_xor(v, 32);
        tsum[nt] = v;
    }
    if (quad == 0) {
#pragma unroll
        for (int nt = 0; nt < 8; nt++) red[wave * 128 + nt * 16 + ln] = tsum[nt];
    }
    __syncthreads();
    if (tid < 128) {
        float v = red[tid] + red[128 + tid] + red[256 + tid] + red[384 + tid];
        unsafeAtomicAdd(&colsum[s * CC + tid], v);
    }
}

// ===========================================================================
// All 4 edge types' attention logits in one pass over h0/h1
// ===========================================================================
__global__ __launch_bounds__(256) void al_all(
    const float* __restrict__ h0, const float* __restrict__ h1,
    const float* __restrict__ asrc, const float* __restrict__ adst,
    float* __restrict__ als4, float* __restrict__ ald4)
{
    const int idx = blockIdx.x * 256 + threadIdx.x;
    if (idx >= NHt) return;
    const int n = idx >> 3, h = idx & 7;
    float r0[16], r1[16];
    const float* p0 = h0 + (size_t)n * CC + h * DD;
    const float* p1 = h1 + (size_t)n * CC + h * DD;
#pragma unroll
    for (int d = 0; d < 16; d += 4) {
        *(float4*)&r0[d] = *(const float4*)&p0[d];
        *(float4*)&r1[d] = *(const float4*)&p1[d];
    }
    const int est[4] = {0, 0, 1, 1}, edt[4] = {0, 1, 0, 1};
#pragma unroll
    for (int e = 0; e < 4; e++) {
        const float* av = asrc + (size_t)(e * HH + h) * DD;
        const float* bv = adst + (size_t)(e * HH + h) * DD;
        const float* hs = est[e] ? r1 : r0;
        const float* hd = edt[e] ? r1 : r0;
        float s1 = 0.f, s2 = 0.f;
#pragma unroll
        for (int d = 0; d < 16; d++) {
            s1 = fmaf(hs[d], av[d], s1);
            s2 = fmaf(hd[d], bv[d], s2);
        }
        als4[e * NHt + idx] = s1;
        ald4[e * NHt + idx] = s2;
    }
}

// ===========================================================================
// Fused edge softmax + aggregate: wave per dst; z in registers (pass 1),
// exp recomputed in pass 2; single relu'd row write. No fp atomics, no exb.
// ===========================================================================
__global__ __launch_bounds__(256) void edge_kernel(
    const int* __restrict__ rowptr, const int* __restrict__ srcs,
    const float* __restrict__ als, const float* __restrict__ ald,
    const float* __restrict__ hsrc, float* __restrict__ o)
{
    const int dst = blockIdx.x * 4 + (threadIdx.x >> 6);
    const int lane = threadIdx.x & 63;
    const int h = lane >> 3;                       // lane owns channels lane*2, lane*2+1
    const float aldv = ald[dst * 8 + h];
    const int p0 = rowptr[dst], p1 = rowptr[dst + 1];
    float zs = 0.f;
    for (int p = p0; p < p1; p++) {
        float sc = als[srcs[p] * 8 + h] + aldv;
        sc = sc > 0.f ? sc : 0.2f * sc;
        zs += __expf(sc);
    }
    const float zinv = zs > 0.f ? 1.f / zs : 0.f;
    float ax = 0.f, ay = 0.f;
    for (int p = p0; p < p1; p++) {
        const int src = srcs[p];
        float sc = als[src * 8 + h] + aldv;
        sc = sc > 0.f ? sc : 0.2f * sc;
        const float alpha = __expf(sc) * zinv;
        const float2 xv = *(const float2*)&hsrc[(size_t)src * CC + lane * 2];
        ax = fmaf(alpha, xv.x, ax);
        ay = fmaf(alpha, xv.y, ay);
    }
    float2 outv = {fmaxf(ax, 0.f), fmaxf(ay, 0.f)};
    *(float2*)&o[(size_t)dst * CC + lane * 2] = outv;
}

// ===========================================================================
// Semantic softmax weights
// ===========================================================================
__global__ __launch_bounds__(128) void attn_kernel(
    const float* __restrict__ colsum, const float* __restrict__ q,
    float* __restrict__ attn)
{
    const int tid = threadIdx.x;
    const float qc = q[tid];
    __shared__ float part[2][4];
    float p[4];
#pragma unroll
    for (int s = 0; s < 4; s++) {
        float v = qc * colsum[s * CC + tid];
        for (int off = 32; off > 0; off >>= 1) v += __shfl_down(v, off);
        p[s] = v;
    }
    if ((tid & 63) == 0) {
        int w = tid >> 6;
#pragma unroll
        for (int s = 0; s < 4; s++) part[w][s] = p[s];
    }
    __syncthreads();
    if (tid == 0) {
        float sc[4];
#pragma unroll
        for (int s = 0; s < 4; s++) sc[s] = (part[0][s] + part[1][s]) / (float)NN;
#pragma unroll
        for (int t = 0; t < 2; t++) {
            float m = fmaxf(sc[2 * t], sc[2 * t + 1]);
            float e0 = expf(sc[2 * t] - m), e1 = expf(sc[2 * t + 1] - m);
            float inv = 1.f / (e0 + e1);
            attn[2 * t] = e0 * inv;
            attn[2 * t + 1] = e1 * inv;
        }
    }
}

__global__ __launch_bounds__(256) void combine_kernel(
    const float* __restrict__ o, const float* __restrict__ attn,
    float* __restrict__ x0, float* __restrict__ x1)
{
    const int i = blockIdx.x * 256 + threadIdx.x;
    if (i >= NC) return;
    const float a0 = attn[0], a1 = attn[1], a2 = attn[2], a3 = attn[3];
    x0[i] = a0 * o[i] + a1 * o[(size_t)NC + i];
    x1[i] = a2 * o[2 * (size_t)NC + i] + a3 * o[3 * (size_t)NC + i];
}

// ===========================================================================
// Pooling + head (unchanged from passing version)
// ===========================================================================
__global__ __launch_bounds__(256) void pool_kernel(
    const float* __restrict__ x0, const float* __restrict__ x1,
    const int* __restrict__ b0, const int* __restrict__ b1,
    float* __restrict__ fmaxb, float* __restrict__ fsumb)
{
    const int t = blockIdx.y;
    const float* x = t ? x1 : x0;
    const int* batch = t ? b1 : b0;
    const int i = blockIdx.x * 256 + threadIdx.x;
    if (i >= (NN / 8) * CC) return;
    const int g = i >> 7, c = i & 127;
    const int n0 = g * 8;
    int curb = batch[n0];
    float vmax = 0.f, vsum = 0.f;
    for (int k = 0; k < 8; k++) {
        int n = n0 + k;
        int b = batch[n];
        float v = x[(size_t)n * CC + c];
        if (b != curb) {
            atomicMax((unsigned*)&fmaxb[(t * BBg + curb) * CC + c], __float_as_uint(vmax));
            unsafeAtomicAdd(&fsumb[(t * BBg + curb) * CC + c], vsum);
            curb = b; vmax = 0.f; vsum = 0.f;
        }
        vmax = fmaxf(vmax, v);
        vsum += v;
    }
    atomicMax((unsigned*)&fmaxb[(t * BBg + curb) * CC + c], __float_as_uint(vmax));
    unsafeAtomicAdd(&fsumb[(t * BBg + curb) * CC + c], vsum);
}

__global__ void cnt_kernel(const int* __restrict__ b0, const int* __restrict__ b1,
                           float* __restrict__ cnt)
{
    const int tid = threadIdx.x;
    if (tid >= 2 * BBg) return;
    const int* batch = (tid >= BBg) ? b1 : b0;
    const int b = tid & (BBg - 1);
    int lo0 = 0, hi0 = NN;
    while (lo0 < hi0) { int mid = (lo0 + hi0) >> 1; if (batch[mid] < b) lo0 = mid + 1; else hi0 = mid; }
    int lo1 = lo0, hi1 = NN;
    while (lo1 < hi1) { int mid = (lo1 + hi1) >> 1; if (batch[mid] < b + 1) lo1 = mid + 1; else hi1 = mid; }
    cnt[tid] = (float)(lo1 - lo0);
}

__global__ __launch_bounds__(512) void head_kernel(
    const float* __restrict__ fmaxb, const float* __restrict__ fsumb,
    const float* __restrict__ cnt,
    const float* __restrict__ W1, const float* __restrict__ bb1,
    const float* __restrict__ W2, const float* __restrict__ bb2,
    const float* __restrict__ W3, const float* __restrict__ bb3,
    float* __restrict__ out)
{
    __shared__ float F[32][512];
    __shared__ float scale[32];
    __shared__ float H1s[32][128];
    __shared__ float H2s[32][64];
    const int tid = threadIdx.x;
    const int j = tid;
    const int tt = j >> 8;
    const int jj = j & 255;
    const bool ismax = jj < 128;
    const int c = jj & 127;
    float csum = 0.f;
    for (int b = 0; b < 32; b++) {
        float v;
        if (ismax) v = fmaxb[(tt * BBg + b) * CC + c];
        else       v = fsumb[(tt * BBg + b) * CC + c] / fmaxf(cnt[tt * BBg + b], 1.f);
        F[b][j] = v;
        csum += v;
    }
    const float cmean = csum * (1.f / 32.f);
    for (int b = 0; b < 32; b++) F[b][j] -= cmean;
    __syncthreads();
    {
        const int b = tid >> 4, l = tid & 15;
        float s = 0.f;
        for (int jx = l; jx < 512; jx += 16) { float v = F[b][jx]; s += v * v; }
        for (int off = 8; off > 0; off >>= 1) s += __shfl_down(s, off);
        if (l == 0) scale[b] = 100.f / sqrtf(1e-6f + s);
    }
    __syncthreads();
    for (int b = 0; b < 32; b++) F[b][j] *= scale[b];
    __syncthreads();
    {
        const int co = tid & 127, bg = tid >> 7;
        float acc[8] = {};
        for (int k = 0; k < 512; k++) {
            float w = W1[k * 128 + co];
#pragma unroll
            for (int r = 0; r < 8; r++) acc[r] = fmaf(F[bg * 8 + r][k], w, acc[r]);
        }
        float bv = bb1[co];
#pragma unroll
        for (int r = 0; r < 8; r++) H1s[bg * 8 + r][co] = fmaxf(acc[r] + bv, 0.f);
    }
    __syncthreads();
    {
        const int co = tid & 63, bg = tid >> 6;
        float acc[4] = {};
        for (int k = 0; k < 128; k++) {
            float w = W2[k * 64 + co];
#pragma unroll
            for (int r = 0; r < 4; r++) acc[r] = fmaf(H1s[bg * 4 + r][k], w, acc[r]);
        }
        float bv = bb2[co];
#pragma unroll
        for (int r = 0; r < 4; r++) H2s[bg * 4 + r][co] = fmaxf(acc[r] + bv, 0.f);
    }
    __syncthreads();
    if (tid < 64) {
        const int b = tid >> 1, oc = tid & 1;
        float acc = bb3[oc];
        for (int k = 0; k < 64; k++) acc = fmaf(H2s[b][k], W3[k * 2 + oc], acc);
        out[b * 2 + oc] = acc;
    }
}

// ===========================================================================
extern "C" void kernel_launch(void* const* d_in, const int* in_sizes, int n_in,
                              void* d_out, int out_size, void* d_ws, size_t ws_size,
                              hipStream_t stream)
{
    const float* x_bold = (const float*)d_in[0];
    const float* x_dti  = (const float*)d_in[1];
    const float* proj_w = (const float*)d_in[2];
    const float* proj_b = (const float*)d_in[3];
    const float* a_src  = (const float*)d_in[4];
    const float* a_dst  = (const float*)d_in[5];
    const float* k_w    = (const float*)d_in[6];
    const float* k_b    = (const float*)d_in[7];
    const float* qv     = (const float*)d_in[8];
    const float* lin1_w = (const float*)d_in[9];
    const float* lin1_b = (const float*)d_in[10];
    const float* lin2_w = (const float*)d_in[11];
    const float* lin2_b = (const float*)d_in[12];
    const float* lin3_w = (const float*)d_in[13];
    const float* lin3_b = (const float*)d_in[14];
    const int* eis[4] = {(const int*)d_in[15], (const int*)d_in[16],
                         (const int*)d_in[17], (const int*)d_in[18]};
    const int* batch_bold = (const int*)d_in[19];
    const int* batch_dti  = (const int*)d_in[20];

    float* ws = (float*)d_ws;
    float* h0   = ws;                       // [N,C]
    float* h1   = h0 + NC;                  // [N,C]
    float* obuf = h1 + NC;                  // 4x[N,C]
    float* x0   = obuf + 4 * (size_t)NC;    // [N,C]
    float* x1   = x0 + NC;                  // [N,C]
    float* als4 = x1 + NC;                  // [4][N,H]
    float* ald4 = als4 + 4 * (size_t)NHt;   // [4][N,H]
    float* colsum = ald4 + 4 * (size_t)NHt; // [4,C]
    float* attn   = colsum + 4 * CC;        // [4]
    float* fmaxb  = attn + 4;               // [2,B,C]
    float* fsumb  = fmaxb + 2 * BBg * CC;   // [2,B,C]
    float* cnt    = fsumb + 2 * BBg * CC;   // [2,B]
    char* pc = (char*)(cnt + 2 * BBg);
    pc = (char*)(((uintptr_t)pc + 15) & ~(uintptr_t)15);
    unsigned short* wt_hi = (unsigned short*)pc;     // [9][128][128] bf16 (transposed)
    unsigned short* wt_lo = wt_hi + 9 * 16384;
    int* deg    = (int*)(wt_lo + 9 * 16384);
    int* cursor = deg + NN;
    int* rowptr[4]; int* srcs[4];
    int* ip = cursor + NN;
    for (int e = 0; e < 4; e++) { rowptr[e] = ip; ip += NN + 1; srcs[e] = ip; ip += NE; }

    // ---- CSR per edge type + weight prep (edge lists / weights constant) ----
    for (int e = 0; e < 4; e++) {
        hipMemsetAsync(deg, 0, NN * sizeof(int), stream);
        hist_kernel<<<(NE + 255) / 256, 256, 0, stream>>>(eis[e], deg);
        scan_kernel<<<1, 1024, 0, stream>>>(deg, rowptr[e], cursor);
        scatter_kernel<<<(NE + 255) / 256, 256, 0, stream>>>(eis[e], cursor, srcs[e]);
    }
    wprep_kernel<<<(9 * 16384 + 255) / 256, 256, 0, stream>>>(proj_w, k_w, wt_hi, wt_lo);

    hipMemcpyAsync(x0, x_bold, (size_t)NC * sizeof(float), hipMemcpyDeviceToDevice, stream);
    hipMemcpyAsync(x1, x_dti,  (size_t)NC * sizeof(float), hipMemcpyDeviceToDevice, stream);

    const int est[4] = {0, 0, 1, 1};
    const int eoi[4] = {0, 2, 1, 3};

    for (int l = 0; l < 3; l++) {
        proj_mfma<<<dim3(157, 2), 256, 0, stream>>>(
            x0, x1, wt_hi + (size_t)l * 2 * 16384, wt_lo + (size_t)l * 2 * 16384,
            proj_b + (size_t)l * 2 * CC, h0, h1);
        al_all<<<625, 256, 0, stream>>>(
            h0, h1, a_src + (size_t)l * 4 * HH * DD, a_dst + (size_t)l * 4 * HH * DD,
            als4, ald4);
        for (int e = 0; e < 4; e++) {
            edge_kernel<<<NN / 4, 256, 0, stream>>>(
                rowptr[e], srcs[e], als4 + (size_t)e * NHt, ald4 + (size_t)e * NHt,
                est[e] ? h1 : h0, obuf + (size_t)eoi[e] * NC);
        }
        hipMemsetAsync(colsum, 0, 4 * CC * sizeof(float), stream);
        semcol_mfma<<<dim3(157, 4), 256, 0, stream>>>(
            obuf, wt_hi + (size_t)(6 + l) * 16384, wt_lo + (size_t)(6 + l) * 16384,
            k_b + (size_t)l * CC, colsum);
        attn_kernel<<<1, 128, 0, stream>>>(colsum, qv + l * CC, attn);
        combine_kernel<<<(NC + 255) / 256, 256, 0, stream>>>(obuf, attn, x0, x1);
    }

    hipMemsetAsync(fmaxb, 0, 2 * 2 * BBg * CC * sizeof(float), stream);
    pool_kernel<<<dim3((NN / 8) * CC / 256, 2), 256, 0, stream>>>(
        x0, x1, batch_bold, batch_dti, fmaxb, fsumb);
    cnt_kernel<<<1, 64, 0, stream>>>(batch_bold, batch_dti, cnt);
    head_kernel<<<1, 512, 0, stream>>>(fmaxb, fsumb, cnt, lin1_w, lin1_b,
                                       lin2_w, lin2_b, lin3_w, lin3_b, (float*)d_out);
}

// Round 4
// 940.253 us; speedup vs baseline: 1.8693x; 1.8693x over previous
//
#include <hip/hip_runtime.h>

#define NN 20000
#define NE 400000
#define CC 128
#define HH 8
#define DD 16
#define BBg 32
#define NC (NN * CC)      // 2,560,000
#define NHt (NN * HH)     // 160,000

typedef __attribute__((ext_vector_type(8))) short short8;
typedef __attribute__((ext_vector_type(4))) float floatx4;

__device__ inline unsigned short bf16_trunc(float f) {
    return (unsigned short)(__float_as_uint(f) >> 16);
}

// ===========================================================================
// CSR build, batched over the 4 edge types (grid.y / blockIdx.x = type)
// ===========================================================================
__global__ __launch_bounds__(256) void hist_all(
    const int* __restrict__ e0, const int* __restrict__ e1,
    const int* __restrict__ e2, const int* __restrict__ e3,
    int* __restrict__ deg4)
{
    const int y = blockIdx.y;
    const int* ei = (y == 0) ? e0 : (y == 1) ? e1 : (y == 2) ? e2 : e3;
    const int e = blockIdx.x * 256 + threadIdx.x;
    if (e >= NE) return;
    atomicAdd(&deg4[y * NN + ei[NE + e]], 1);
}

__global__ __launch_bounds__(1024) void scan_all(const int* __restrict__ deg4,
                                                 int* __restrict__ rowptr4,
                                                 int* __restrict__ cursor4)
{
    const int* deg = deg4 + blockIdx.x * NN;
    int* rowptr = rowptr4 + blockIdx.x * (NN + 1);
    int* cursor = cursor4 + blockIdx.x * NN;
    __shared__ int part[1024];
    const int tid = threadIdx.x;
    const int base = tid * 20;
    int s = 0;
    for (int k = 0; k < 20; k++) { int i = base + k; if (i < NN) s += deg[i]; }
    part[tid] = s;
    __syncthreads();
    if (tid == 0) {
        int run = 0;
        for (int i = 0; i < 1024; i++) { int t = part[i]; part[i] = run; run += t; }
        rowptr[NN] = run;
    }
    __syncthreads();
    int run = part[tid];
    for (int k = 0; k < 20; k++) {
        int i = base + k;
        if (i < NN) { rowptr[i] = run; cursor[i] = run; run += deg[i]; }
    }
}

__global__ __launch_bounds__(256) void scatter_all(
    const int* __restrict__ e0, const int* __restrict__ e1,
    const int* __restrict__ e2, const int* __restrict__ e3,
    int* __restrict__ cursor4, int* __restrict__ srcs4)
{
    const int y = blockIdx.y;
    const int* ei = (y == 0) ? e0 : (y == 1) ? e1 : (y == 2) ? e2 : e3;
    const int e = blockIdx.x * 256 + threadIdx.x;
    if (e >= NE) return;
    const int pos = atomicAdd(&cursor4[y * NN + ei[NE + e]], 1);
    srcs4[(size_t)y * NE + pos] = ei[e];
}

// ===========================================================================
// W prep: 9 mats fp32 [k][n] -> transposed bf16 hi/lo [n][k] (split-float)
// ===========================================================================
__global__ __launch_bounds__(256) void wprep_kernel(
    const float* __restrict__ proj_w, const float* __restrict__ k_w,
    unsigned short* __restrict__ wt_hi, unsigned short* __restrict__ wt_lo)
{
    const int idx = blockIdx.x * 256 + threadIdx.x;
    if (idx >= 9 * 16384) return;
    const int mat = idx >> 14, r = idx & 16383;
    const int n = r >> 7, k = r & 127;
    const float* W = (mat < 6) ? (proj_w + (size_t)mat * 16384)
                               : (k_w + (size_t)(mat - 6) * 16384);
    float f = W[k * 128 + n];
    unsigned short hi = bf16_trunc(f);
    float fh = __uint_as_float((unsigned)hi << 16);
    wt_hi[idx] = hi;
    wt_lo[idx] = bf16_trunc(f - fh);
}

// ===========================================================================
// MFMA GEMMs (unchanged from round 3)
// ===========================================================================
__global__ __launch_bounds__(256) void proj_mfma(
    const float* __restrict__ X0, const float* __restrict__ X1,
    const unsigned short* __restrict__ whi_l, const unsigned short* __restrict__ wlo_l,
    const float* __restrict__ bias_l,
    float* __restrict__ Y0, float* __restrict__ Y1)
{
    const int t = blockIdx.y;
    const float* X = t ? X1 : X0;
    const unsigned short* whi = whi_l + (size_t)t * 16384;
    const unsigned short* wlo = wlo_l + (size_t)t * 16384;
    const float* bias = bias_l + t * CC;
    float* Y = t ? Y1 : Y0;

    __shared__ unsigned short Bh[128 * 136];
    __shared__ unsigned short Bl[128 * 136];
    const int tid = threadIdx.x;
    for (int i = tid; i < 128 * 16; i += 256) {
        int n = i >> 4, ch = (i & 15) * 8;
        *(short8*)&Bh[n * 136 + ch] = *(const short8*)&whi[n * 128 + ch];
        *(short8*)&Bl[n * 136 + ch] = *(const short8*)&wlo[n * 128 + ch];
    }
    __syncthreads();

    const int wave = tid >> 6, lane = tid & 63;
    const int ln = lane & 15, quad = lane >> 4;
    const int rW = blockIdx.x * 128 + wave * 32;

    floatx4 acc[2][8];
#pragma unroll
    for (int mh = 0; mh < 2; mh++)
#pragma unroll
        for (int nt = 0; nt < 8; nt++) acc[mh][nt] = (floatx4){0.f, 0.f, 0.f, 0.f};

    for (int ki = 0; ki < 4; ki++) {
        short8 ahi[2], alo[2];
#pragma unroll
        for (int mh = 0; mh < 2; mh++) {
            int row = rW + mh * 16 + ln; if (row > NN - 1) row = NN - 1;
            const float* ap = X + (size_t)row * CC + ki * 32 + quad * 8;
            float4 a0 = *(const float4*)ap;
            float4 a1 = *(const float4*)(ap + 4);
            float av[8] = {a0.x, a0.y, a0.z, a0.w, a1.x, a1.y, a1.z, a1.w};
#pragma unroll
            for (int j = 0; j < 8; j++) {
                unsigned short h = bf16_trunc(av[j]);
                float fh = __uint_as_float((unsigned)h << 16);
                ahi[mh][j] = (short)h;
                alo[mh][j] = (short)bf16_trunc(av[j] - fh);
            }
        }
        const int kb = ki * 32 + quad * 8;
#pragma unroll
        for (int nt = 0; nt < 8; nt++) {
            short8 bh = *(const short8*)&Bh[(nt * 16 + ln) * 136 + kb];
            short8 bl = *(const short8*)&Bl[(nt * 16 + ln) * 136 + kb];
#pragma unroll
            for (int mh = 0; mh < 2; mh++) {
                acc[mh][nt] = __builtin_amdgcn_mfma_f32_16x16x32_bf16(ahi[mh], bh, acc[mh][nt], 0, 0, 0);
                acc[mh][nt] = __builtin_amdgcn_mfma_f32_16x16x32_bf16(alo[mh], bh, acc[mh][nt], 0, 0, 0);
                acc[mh][nt] = __builtin_amdgcn_mfma_f32_16x16x32_bf16(ahi[mh], bl, acc[mh][nt], 0, 0, 0);
            }
        }
    }
#pragma unroll
    for (int mh = 0; mh < 2; mh++)
#pragma unroll
        for (int nt = 0; nt < 8; nt++) {
            float bv = bias[nt * 16 + ln];
#pragma unroll
            for (int r = 0; r < 4; r++) {
                int row = rW + mh * 16 + quad * 4 + r;
                if (row < NN) Y[(size_t)row * CC + nt * 16 + ln] = acc[mh][nt][r] + bv;
            }
        }
}

__global__ __launch_bounds__(256) void semcol_mfma(
    const float* __restrict__ Obase,
    const unsigned short* __restrict__ whi, const unsigned short* __restrict__ wlo,
    const float* __restrict__ Kb, float* __restrict__ colsum)
{
    const int s = blockIdx.y;
    const float* X = Obase + (size_t)s * NC;

    __shared__ unsigned short Bh[128 * 136];
    __shared__ unsigned short Bl[128 * 136];
    __shared__ float red[4 * 128];
    const int tid = threadIdx.x;
    for (int i = tid; i < 128 * 16; i += 256) {
        int n = i >> 4, ch = (i & 15) * 8;
        *(short8*)&Bh[n * 136 + ch] = *(const short8*)&whi[n * 128 + ch];
        *(short8*)&Bl[n * 136 + ch] = *(const short8*)&wlo[n * 128 + ch];
    }
    __syncthreads();

    const int wave = tid >> 6, lane = tid & 63;
    const int ln = lane & 15, quad = lane >> 4;
    const int rW = blockIdx.x * 128 + wave * 32;

    floatx4 acc[2][8];
#pragma unroll
    for (int mh = 0; mh < 2; mh++)
#pragma unroll
        for (int nt = 0; nt < 8; nt++) acc[mh][nt] = (floatx4){0.f, 0.f, 0.f, 0.f};

    for (int ki = 0; ki < 4; ki++) {
        short8 ahi[2], alo[2];
#pragma unroll
        for (int mh = 0; mh < 2; mh++) {
            int row = rW + mh * 16 + ln; if (row > NN - 1) row = NN - 1;
            const float* ap = X + (size_t)row * CC + ki * 32 + quad * 8;
            float4 a0 = *(const float4*)ap;
            float4 a1 = *(const float4*)(ap + 4);
            float av[8] = {a0.x, a0.y, a0.z, a0.w, a1.x, a1.y, a1.z, a1.w};
#pragma unroll
            for (int j = 0; j < 8; j++) {
                unsigned short h = bf16_trunc(av[j]);
                float fh = __uint_as_float((unsigned)h << 16);
                ahi[mh][j] = (short)h;
                alo[mh][j] = (short)bf16_trunc(av[j] - fh);
            }
        }
        const int kb = ki * 32 + quad * 8;
#pragma unroll
        for (int nt = 0; nt < 8; nt++) {
            short8 bh = *(const short8*)&Bh[(nt * 16 + ln) * 136 + kb];
            short8 bl = *(const short8*)&Bl[(nt * 16 + ln) * 136 + kb];
#pragma unroll
            for (int mh = 0; mh < 2; mh++) {
                acc[mh][nt] = __builtin_amdgcn_mfma_f32_16x16x32_bf16(ahi[mh], bh, acc[mh][nt], 0, 0, 0);
                acc[mh][nt] = __builtin_amdgcn_mfma_f32_16x16x32_bf16(alo[mh], bh, acc[mh][nt], 0, 0, 0);
                acc[mh][nt] = __builtin_amdgcn_mfma_f32_16x16x32_bf16(ahi[mh], bl, acc[mh][nt], 0, 0, 0);
            }
        }
    }
    float tsum[8];
#pragma unroll
    for (int nt = 0; nt < 8; nt++) {
        float bv = Kb[nt * 16 + ln];
        float v = 0.f;
#pragma unroll
        for (int mh = 0; mh < 2; mh++)
#pragma unroll
            for (int r = 0; r < 4; r++) {
                int row = rW + mh * 16 + quad * 4 + r;
                if (row < NN) v += tanhf(acc[mh][nt][r] + bv);
            }
        v += __shfl_xor(v, 16);
        v += __shfl_xor(v, 32);
        tsum[nt] = v;
    }
    if (quad == 0) {
#pragma unroll
        for (int nt = 0; nt < 8; nt++) red[wave * 128 + nt * 16 + ln] = tsum[nt];
    }
    __syncthreads();
    if (tid < 128) {
        float v = red[tid] + red[128 + tid] + red[256 + tid] + red[384 + tid];
        unsafeAtomicAdd(&colsum[s * CC + tid], v);
    }
}

// ===========================================================================
// All 4 edge types' attention logits in one pass over h0/h1
// ===========================================================================
__global__ __launch_bounds__(256) void al_all(
    const float* __restrict__ h0, const float* __restrict__ h1,
    const float* __restrict__ asrc, const float* __restrict__ adst,
    float* __restrict__ als4, float* __restrict__ ald4)
{
    const int idx = blockIdx.x * 256 + threadIdx.x;
    if (idx >= NHt) return;
    const int n = idx >> 3, h = idx & 7;
    float r0[16], r1[16];
    const float* p0 = h0 + (size_t)n * CC + h * DD;
    const float* p1 = h1 + (size_t)n * CC + h * DD;
#pragma unroll
    for (int d = 0; d < 16; d += 4) {
        *(float4*)&r0[d] = *(const float4*)&p0[d];
        *(float4*)&r1[d] = *(const float4*)&p1[d];
    }
    const int est[4] = {0, 0, 1, 1}, edt[4] = {0, 1, 0, 1};
#pragma unroll
    for (int e = 0; e < 4; e++) {
        const float* av = asrc + (size_t)(e * HH + h) * DD;
        const float* bv = adst + (size_t)(e * HH + h) * DD;
        const float* hs = est[e] ? r1 : r0;
        const float* hd = edt[e] ? r1 : r0;
        float s1 = 0.f, s2 = 0.f;
#pragma unroll
        for (int d = 0; d < 16; d++) {
            s1 = fmaf(hs[d], av[d], s1);
            s2 = fmaf(hd[d], bv[d], s2);
        }
        als4[e * NHt + idx] = s1;
        ald4[e * NHt + idx] = s2;
    }
}

// ===========================================================================
// Fully-fused edge pass, SINGLE loop: o[dst] = relu( (Σ_e ex_e·x_src) / Σ_e ex_e ).
// One wave per dst; half-waves split the edge list (chain 20->10); float4 channels;
// manual unroll-4 batches index+row loads for memory-level parallelism.
// ===========================================================================
__global__ __launch_bounds__(256) void edge_fused(
    const int* __restrict__ rowptr, const int* __restrict__ srcs,
    const float* __restrict__ als, const float* __restrict__ ald,
    const float* __restrict__ hsrc, float* __restrict__ o)
{
    const int dst = blockIdx.x * 4 + (threadIdx.x >> 6);
    const int lane = threadIdx.x & 63;
    const int half = lane >> 5;          // edge-subset selector
    const int l32 = lane & 31;           // channel group: c = l32*4
    const int h = l32 >> 2;
    const float aldv = ald[dst * 8 + h];
    const int p0 = rowptr[dst], p1 = rowptr[dst + 1];
    const size_t cofs = (size_t)l32 * 4;
    float4 acc = {0.f, 0.f, 0.f, 0.f};
    float zs = 0.f;
    int p = p0 + half;

#define EDGE_STEP(sv, av) {                                                   \
        float sc_ = av + aldv;                                                \
        sc_ = sc_ > 0.f ? sc_ : 0.2f * sc_;                                   \
        const float e_ = __expf(sc_);                                         \
        zs += e_;                                                             \
        const float4 xv_ = *(const float4*)&hsrc[(size_t)(sv) * CC + cofs];   \
        acc.x = fmaf(e_, xv_.x, acc.x);                                       \
        acc.y = fmaf(e_, xv_.y, acc.y);                                       \
        acc.z = fmaf(e_, xv_.z, acc.z);                                       \
        acc.w = fmaf(e_, xv_.w, acc.w);                                       \
    }

    for (; p + 6 < p1; p += 8) {
        const int s0 = srcs[p], s1 = srcs[p + 2], s2 = srcs[p + 4], s3 = srcs[p + 6];
        const float a0 = als[s0 * 8 + h], a1 = als[s1 * 8 + h];
        const float a2 = als[s2 * 8 + h], a3 = als[s3 * 8 + h];
        EDGE_STEP(s0, a0); EDGE_STEP(s1, a1); EDGE_STEP(s2, a2); EDGE_STEP(s3, a3);
    }
    for (; p < p1; p += 2) {
        const int s0 = srcs[p];
        const float a0 = als[s0 * 8 + h];
        EDGE_STEP(s0, a0);
    }
#undef EDGE_STEP

    // combine the two half-wave partial sums
    acc.x += __shfl_xor(acc.x, 32);
    acc.y += __shfl_xor(acc.y, 32);
    acc.z += __shfl_xor(acc.z, 32);
    acc.w += __shfl_xor(acc.w, 32);
    zs    += __shfl_xor(zs, 32);
    if (half == 0) {
        const float zinv = zs > 0.f ? 1.f / zs : 0.f;
        float4 outv = {fmaxf(acc.x * zinv, 0.f), fmaxf(acc.y * zinv, 0.f),
                       fmaxf(acc.z * zinv, 0.f), fmaxf(acc.w * zinv, 0.f)};
        *(float4*)&o[(size_t)dst * CC + cofs] = outv;
    }
}

// ===========================================================================
// Semantic softmax weights
// ===========================================================================
__global__ __launch_bounds__(128) void attn_kernel(
    const float* __restrict__ colsum, const float* __restrict__ q,
    float* __restrict__ attn)
{
    const int tid = threadIdx.x;
    const float qc = q[tid];
    __shared__ float part[2][4];
    float p[4];
#pragma unroll
    for (int s = 0; s < 4; s++) {
        float v = qc * colsum[s * CC + tid];
        for (int off = 32; off > 0; off >>= 1) v += __shfl_down(v, off);
        p[s] = v;
    }
    if ((tid & 63) == 0) {
        int w = tid >> 6;
#pragma unroll
        for (int s = 0; s < 4; s++) part[w][s] = p[s];
    }
    __syncthreads();
    if (tid == 0) {
        float sc[4];
#pragma unroll
        for (int s = 0; s < 4; s++) sc[s] = (part[0][s] + part[1][s]) / (float)NN;
#pragma unroll
        for (int t = 0; t < 2; t++) {
            float m = fmaxf(sc[2 * t], sc[2 * t + 1]);
            float e0 = expf(sc[2 * t] - m), e1 = expf(sc[2 * t + 1] - m);
            float inv = 1.f / (e0 + e1);
            attn[2 * t] = e0 * inv;
            attn[2 * t + 1] = e1 * inv;
        }
    }
}

__global__ __launch_bounds__(256) void combine_kernel(
    const float* __restrict__ o, const float* __restrict__ attn,
    float* __restrict__ x0, float* __restrict__ x1)
{
    const int i = blockIdx.x * 256 + threadIdx.x;
    if (i >= NC) return;
    const float a0 = attn[0], a1 = attn[1], a2 = attn[2], a3 = attn[3];
    x0[i] = a0 * o[i] + a1 * o[(size_t)NC + i];
    x1[i] = a2 * o[2 * (size_t)NC + i] + a3 * o[3 * (size_t)NC + i];
}

// ===========================================================================
// Pooling + head (unchanged)
// ===========================================================================
__global__ __launch_bounds__(256) void pool_kernel(
    const float* __restrict__ x0, const float* __restrict__ x1,
    const int* __restrict__ b0, const int* __restrict__ b1,
    float* __restrict__ fmaxb, float* __restrict__ fsumb)
{
    const int t = blockIdx.y;
    const float* x = t ? x1 : x0;
    const int* batch = t ? b1 : b0;
    const int i = blockIdx.x * 256 + threadIdx.x;
    if (i >= (NN / 8) * CC) return;
    const int g = i >> 7, c = i & 127;
    const int n0 = g * 8;
    int curb = batch[n0];
    float vmax = 0.f, vsum = 0.f;
    for (int k = 0; k < 8; k++) {
        int n = n0 + k;
        int b = batch[n];
        float v = x[(size_t)n * CC + c];
        if (b != curb) {
            atomicMax((unsigned*)&fmaxb[(t * BBg + curb) * CC + c], __float_as_uint(vmax));
            unsafeAtomicAdd(&fsumb[(t * BBg + curb) * CC + c], vsum);
            curb = b; vmax = 0.f; vsum = 0.f;
        }
        vmax = fmaxf(vmax, v);
        vsum += v;
    }
    atomicMax((unsigned*)&fmaxb[(t * BBg + curb) * CC + c], __float_as_uint(vmax));
    unsafeAtomicAdd(&fsumb[(t * BBg + curb) * CC + c], vsum);
}

__global__ void cnt_kernel(const int* __restrict__ b0, const int* __restrict__ b1,
                           float* __restrict__ cnt)
{
    const int tid = threadIdx.x;
    if (tid >= 2 * BBg) return;
    const int* batch = (tid >= BBg) ? b1 : b0;
    const int b = tid & (BBg - 1);
    int lo0 = 0, hi0 = NN;
    while (lo0 < hi0) { int mid = (lo0 + hi0) >> 1; if (batch[mid] < b) lo0 = mid + 1; else hi0 = mid; }
    int lo1 = lo0, hi1 = NN;
    while (lo1 < hi1) { int mid = (lo1 + hi1) >> 1; if (batch[mid] < b + 1) lo1 = mid + 1; else hi1 = mid; }
    cnt[tid] = (float)(lo1 - lo0);
}

__global__ __launch_bounds__(512) void head_kernel(
    const float* __restrict__ fmaxb, const float* __restrict__ fsumb,
    const float* __restrict__ cnt,
    const float* __restrict__ W1, const float* __restrict__ bb1,
    const float* __restrict__ W2, const float* __restrict__ bb2,
    const float* __restrict__ W3, const float* __restrict__ bb3,
    float* __restrict__ out)
{
    __shared__ float F[32][512];
    __shared__ float scale[32];
    __shared__ float H1s[32][128];
    __shared__ float H2s[32][64];
    const int tid = threadIdx.x;
    const int j = tid;
    const int tt = j >> 8;
    const int jj = j & 255;
    const bool ismax = jj < 128;
    const int c = jj & 127;
    float csum = 0.f;
    for (int b = 0; b < 32; b++) {
        float v;
        if (ismax) v = fmaxb[(tt * BBg + b) * CC + c];
        else       v = fsumb[(tt * BBg + b) * CC + c] / fmaxf(cnt[tt * BBg + b], 1.f);
        F[b][j] = v;
        csum += v;
    }
    const float cmean = csum * (1.f / 32.f);
    for (int b = 0; b < 32; b++) F[b][j] -= cmean;
    __syncthreads();
    {
        const int b = tid >> 4, l = tid & 15;
        float s = 0.f;
        for (int jx = l; jx < 512; jx += 16) { float v = F[b][jx]; s += v * v; }
        for (int off = 8; off > 0; off >>= 1) s += __shfl_down(s, off);
        if (l == 0) scale[b] = 100.f / sqrtf(1e-6f + s);
    }
    __syncthreads();
    for (int b = 0; b < 32; b++) F[b][j] *= scale[b];
    __syncthreads();
    {
        const int co = tid & 127, bg = tid >> 7;
        float acc[8] = {};
        for (int k = 0; k < 512; k++) {
            float w = W1[k * 128 + co];
#pragma unroll
            for (int r = 0; r < 8; r++) acc[r] = fmaf(F[bg * 8 + r][k], w, acc[r]);
        }
        float bv = bb1[co];
#pragma unroll
        for (int r = 0; r < 8; r++) H1s[bg * 8 + r][co] = fmaxf(acc[r] + bv, 0.f);
    }
    __syncthreads();
    {
        const int co = tid & 63, bg = tid >> 6;
        float acc[4] = {};
        for (int k = 0; k < 128; k++) {
            float w = W2[k * 64 + co];
#pragma unroll
            for (int r = 0; r < 4; r++) acc[r] = fmaf(H1s[bg * 4 + r][k], w, acc[r]);
        }
        float bv = bb2[co];
#pragma unroll
        for (int r = 0; r < 4; r++) H2s[bg * 4 + r][co] = fmaxf(acc[r] + bv, 0.f);
    }
    __syncthreads();
    if (tid < 64) {
        const int b = tid >> 1, oc = tid & 1;
        float acc = bb3[oc];
        for (int k = 0; k < 64; k++) acc = fmaf(H2s[b][k], W3[k * 2 + oc], acc);
        out[b * 2 + oc] = acc;
    }
}

// ===========================================================================
extern "C" void kernel_launch(void* const* d_in, const int* in_sizes, int n_in,
                              void* d_out, int out_size, void* d_ws, size_t ws_size,
                              hipStream_t stream)
{
    const float* x_bold = (const float*)d_in[0];
    const float* x_dti  = (const float*)d_in[1];
    const float* proj_w = (const float*)d_in[2];
    const float* proj_b = (const float*)d_in[3];
    const float* a_src  = (const float*)d_in[4];
    const float* a_dst  = (const float*)d_in[5];
    const float* k_w    = (const float*)d_in[6];
    const float* k_b    = (const float*)d_in[7];
    const float* qv     = (const float*)d_in[8];
    const float* lin1_w = (const float*)d_in[9];
    const float* lin1_b = (const float*)d_in[10];
    const float* lin2_w = (const float*)d_in[11];
    const float* lin2_b = (const float*)d_in[12];
    const float* lin3_w = (const float*)d_in[13];
    const float* lin3_b = (const float*)d_in[14];
    const int* ei0 = (const int*)d_in[15];
    const int* ei1 = (const int*)d_in[16];
    const int* ei2 = (const int*)d_in[17];
    const int* ei3 = (const int*)d_in[18];
    const int* batch_bold = (const int*)d_in[19];
    const int* batch_dti  = (const int*)d_in[20];

    float* ws = (float*)d_ws;
    float* h0   = ws;                       // [N,C]
    float* h1   = h0 + NC;                  // [N,C]
    float* obuf = h1 + NC;                  // 4x[N,C]
    float* x0   = obuf + 4 * (size_t)NC;    // [N,C]
    float* x1   = x0 + NC;                  // [N,C]
    float* als4 = x1 + NC;                  // [4][N,H]
    float* ald4 = als4 + 4 * (size_t)NHt;   // [4][N,H]
    float* colsum = ald4 + 4 * (size_t)NHt; // [4,C]
    float* attn   = colsum + 4 * CC;        // [4]
    float* fmaxb  = attn + 4;               // [2,B,C]
    float* fsumb  = fmaxb + 2 * BBg * CC;   // [2,B,C]
    float* cnt    = fsumb + 2 * BBg * CC;   // [2,B]
    char* pc = (char*)(cnt + 2 * BBg);
    pc = (char*)(((uintptr_t)pc + 15) & ~(uintptr_t)15);
    unsigned short* wt_hi = (unsigned short*)pc;     // [9][128][128] bf16 (transposed)
    unsigned short* wt_lo = wt_hi + 9 * 16384;
    int* deg4    = (int*)(wt_lo + 9 * 16384);        // [4][N]
    int* cursor4 = deg4 + 4 * NN;                    // [4][N]
    int* rowptr4 = cursor4 + 4 * NN;                 // [4][N+1]
    int* srcs4   = rowptr4 + 4 * (NN + 1);           // [4][E]

    // ---- CSR per edge type (batched) + weight prep ----
    hipMemsetAsync(deg4, 0, 4 * NN * sizeof(int), stream);
    hist_all<<<dim3((NE + 255) / 256, 4), 256, 0, stream>>>(ei0, ei1, ei2, ei3, deg4);
    scan_all<<<4, 1024, 0, stream>>>(deg4, rowptr4, cursor4);
    scatter_all<<<dim3((NE + 255) / 256, 4), 256, 0, stream>>>(ei0, ei1, ei2, ei3,
                                                               cursor4, srcs4);
    wprep_kernel<<<(9 * 16384 + 255) / 256, 256, 0, stream>>>(proj_w, k_w, wt_hi, wt_lo);

    hipMemcpyAsync(x0, x_bold, (size_t)NC * sizeof(float), hipMemcpyDeviceToDevice, stream);
    hipMemcpyAsync(x1, x_dti,  (size_t)NC * sizeof(float), hipMemcpyDeviceToDevice, stream);

    const int est[4] = {0, 0, 1, 1};
    const int eoi[4] = {0, 2, 1, 3};

    for (int l = 0; l < 3; l++) {
        proj_mfma<<<dim3(157, 2), 256, 0, stream>>>(
            x0, x1, wt_hi + (size_t)l * 2 * 16384, wt_lo + (size_t)l * 2 * 16384,
            proj_b + (size_t)l * 2 * CC, h0, h1);
        al_all<<<625, 256, 0, stream>>>(
            h0, h1, a_src + (size_t)l * 4 * HH * DD, a_dst + (size_t)l * 4 * HH * DD,
            als4, ald4);
        for (int e = 0; e < 4; e++) {
            edge_fused<<<NN / 4, 256, 0, stream>>>(
                rowptr4 + (size_t)e * (NN + 1), srcs4 + (size_t)e * NE,
                als4 + (size_t)e * NHt, ald4 + (size_t)e * NHt,
                est[e] ? h1 : h0, obuf + (size_t)eoi[e] * NC);
        }
        hipMemsetAsync(colsum, 0, 4 * CC * sizeof(float), stream);
        semcol_mfma<<<dim3(157, 4), 256, 0, stream>>>(
            obuf, wt_hi + (size_t)(6 + l) * 16384, wt_lo + (size_t)(6 + l) * 16384,
            k_b + (size_t)l * CC, colsum);
        attn_kernel<<<1, 128, 0, stream>>>(colsum, qv + l * CC, attn);
        combine_kernel<<<(NC + 255) / 256, 256, 0, stream>>>(obuf, attn, x0, x1);
    }

    hipMemsetAsync(fmaxb, 0, 2 * 2 * BBg * CC * sizeof(float), stream);
    pool_kernel<<<dim3((NN / 8) * CC / 256, 2), 256, 0, stream>>>(
        x0, x1, batch_bold, batch_dti, fmaxb, fsumb);
    cnt_kernel<<<1, 64, 0, stream>>>(batch_bold, batch_dti, cnt);
    head_kernel<<<1, 512, 0, stream>>>(fmaxb, fsumb, cnt, lin1_w, lin1_b,
                                       lin2_w, lin2_b, lin3_w, lin3_b, (float*)d_out);
}

// Round 5
// 875.425 us; speedup vs baseline: 2.0077x; 1.0741x over previous
//
#include <hip/hip_runtime.h>

#define NN 20000
#define NE 400000
#define CC 128
#define HH 8
#define DD 16
#define BBg 32
#define NC (NN * CC)      // 2,560,000
#define NHt (NN * HH)     // 160,000
#define RSZ 5000          // dst-window size for CSR build (4 passes)

typedef __attribute__((ext_vector_type(8))) short short8;
typedef __attribute__((ext_vector_type(4))) float floatx4;

__device__ inline unsigned short bf16_trunc(float f) {
    return (unsigned short)(__float_as_uint(f) >> 16);
}

// ===========================================================================
// CSR build, batched over 4 edge types; windowed by dst range so random
// 4B writes/atomics accumulate in a small L2/LLC-resident window per pass.
// ===========================================================================
__global__ __launch_bounds__(256) void hist_all(
    const int* __restrict__ e0, const int* __restrict__ e1,
    const int* __restrict__ e2, const int* __restrict__ e3,
    int* __restrict__ deg4)
{
    const int y = blockIdx.y;
    const int* ei = (y == 0) ? e0 : (y == 1) ? e1 : (y == 2) ? e2 : e3;
    const int e = blockIdx.x * 256 + threadIdx.x;
    if (e >= NE) return;
    const int dst = ei[NE + e];
#pragma unroll
    for (int p = 0; p < 4; p++) {
        const int lo = p * RSZ;
        if (dst >= lo && dst < lo + RSZ)
            atomicAdd(&deg4[y * NN + dst], 1);
    }
}

__global__ __launch_bounds__(1024) void scan_all(const int* __restrict__ deg4,
                                                 int* __restrict__ rowptr4,
                                                 int* __restrict__ cursor4)
{
    const int* deg = deg4 + blockIdx.x * NN;
    int* rowptr = rowptr4 + blockIdx.x * (NN + 1);
    int* cursor = cursor4 + blockIdx.x * NN;
    __shared__ int part[1024];
    const int tid = threadIdx.x;
    const int base = tid * 20;
    int s = 0;
    for (int k = 0; k < 20; k++) { int i = base + k; if (i < NN) s += deg[i]; }
    part[tid] = s;
    __syncthreads();
    if (tid == 0) {
        int run = 0;
        for (int i = 0; i < 1024; i++) { int t = part[i]; part[i] = run; run += t; }
        rowptr[NN] = run;
    }
    __syncthreads();
    int run = part[tid];
    for (int k = 0; k < 20; k++) {
        int i = base + k;
        if (i < NN) { rowptr[i] = run; cursor[i] = run; run += deg[i]; }
    }
}

__global__ __launch_bounds__(256) void scatter_all(
    const int* __restrict__ e0, const int* __restrict__ e1,
    const int* __restrict__ e2, const int* __restrict__ e3,
    int* __restrict__ cursor4, int* __restrict__ srcs4)
{
    const int y = blockIdx.y;
    const int* ei = (y == 0) ? e0 : (y == 1) ? e1 : (y == 2) ? e2 : e3;
    const int e = blockIdx.x * 256 + threadIdx.x;
    if (e >= NE) return;
    const int dst = ei[NE + e];
    const int src = ei[e];
#pragma unroll
    for (int p = 0; p < 4; p++) {
        const int lo = p * RSZ;
        if (dst >= lo && dst < lo + RSZ) {
            const int pos = atomicAdd(&cursor4[y * NN + dst], 1);
            srcs4[(size_t)y * NE + pos] = src;
        }
    }
}

// ===========================================================================
// W prep: 9 mats fp32 [k][n] -> transposed bf16 hi/lo [n][k] (split-float)
// ===========================================================================
__global__ __launch_bounds__(256) void wprep_kernel(
    const float* __restrict__ proj_w, const float* __restrict__ k_w,
    unsigned short* __restrict__ wt_hi, unsigned short* __restrict__ wt_lo)
{
    const int idx = blockIdx.x * 256 + threadIdx.x;
    if (idx >= 9 * 16384) return;
    const int mat = idx >> 14, r = idx & 16383;
    const int n = r >> 7, k = r & 127;
    const float* W = (mat < 6) ? (proj_w + (size_t)mat * 16384)
                               : (k_w + (size_t)(mat - 6) * 16384);
    float f = W[k * 128 + n];
    unsigned short hi = bf16_trunc(f);
    float fh = __uint_as_float((unsigned)hi << 16);
    wt_hi[idx] = hi;
    wt_lo[idx] = bf16_trunc(f - fh);
}

// ===========================================================================
// proj GEMM with fused "combine": A row = ca*Xa[row] + cb*Xb[row]
// (attnp==nullptr -> ca=1, cb=0, Xb ignored). Split-bf16 hi/lo, 3 MFMAs.
// ===========================================================================
__global__ __launch_bounds__(256) void proj_mfma(
    const float* __restrict__ XA0, const float* __restrict__ XB0,
    const float* __restrict__ XA1, const float* __restrict__ XB1,
    const float* __restrict__ attnp,
    const unsigned short* __restrict__ whi_l, const unsigned short* __restrict__ wlo_l,
    const float* __restrict__ bias_l,
    float* __restrict__ Y0, float* __restrict__ Y1)
{
    const int t = blockIdx.y;
    const float* Xa = t ? XA1 : XA0;
    const float* Xb = t ? XB1 : XB0;
    float ca = 1.f, cb = 0.f;
    if (attnp) { ca = attnp[2 * t]; cb = attnp[2 * t + 1]; } else { Xb = Xa; }
    const unsigned short* whi = whi_l + (size_t)t * 16384;
    const unsigned short* wlo = wlo_l + (size_t)t * 16384;
    const float* bias = bias_l + t * CC;
    float* Y = t ? Y1 : Y0;

    __shared__ unsigned short Bh[128 * 136];
    __shared__ unsigned short Bl[128 * 136];
    const int tid = threadIdx.x;
    for (int i = tid; i < 128 * 16; i += 256) {
        int n = i >> 4, ch = (i & 15) * 8;
        *(short8*)&Bh[n * 136 + ch] = *(const short8*)&whi[n * 128 + ch];
        *(short8*)&Bl[n * 136 + ch] = *(const short8*)&wlo[n * 128 + ch];
    }
    __syncthreads();

    const int wave = tid >> 6, lane = tid & 63;
    const int ln = lane & 15, quad = lane >> 4;
    const int rW = blockIdx.x * 128 + wave * 32;

    floatx4 acc[2][8];
#pragma unroll
    for (int mh = 0; mh < 2; mh++)
#pragma unroll
        for (int nt = 0; nt < 8; nt++) acc[mh][nt] = (floatx4){0.f, 0.f, 0.f, 0.f};

    for (int ki = 0; ki < 4; ki++) {
        short8 ahi[2], alo[2];
#pragma unroll
        for (int mh = 0; mh < 2; mh++) {
            int row = rW + mh * 16 + ln; if (row > NN - 1) row = NN - 1;
            const size_t ofs = (size_t)row * CC + ki * 32 + quad * 8;
            float4 a0 = *(const float4*)&Xa[ofs];
            float4 a1 = *(const float4*)&Xa[ofs + 4];
            float4 b0 = *(const float4*)&Xb[ofs];
            float4 b1 = *(const float4*)&Xb[ofs + 4];
            float av[8] = {fmaf(cb, b0.x, ca * a0.x), fmaf(cb, b0.y, ca * a0.y),
                           fmaf(cb, b0.z, ca * a0.z), fmaf(cb, b0.w, ca * a0.w),
                           fmaf(cb, b1.x, ca * a1.x), fmaf(cb, b1.y, ca * a1.y),
                           fmaf(cb, b1.z, ca * a1.z), fmaf(cb, b1.w, ca * a1.w)};
#pragma unroll
            for (int j = 0; j < 8; j++) {
                unsigned short h = bf16_trunc(av[j]);
                float fh = __uint_as_float((unsigned)h << 16);
                ahi[mh][j] = (short)h;
                alo[mh][j] = (short)bf16_trunc(av[j] - fh);
            }
        }
        const int kb = ki * 32 + quad * 8;
#pragma unroll
        for (int nt = 0; nt < 8; nt++) {
            short8 bh = *(const short8*)&Bh[(nt * 16 + ln) * 136 + kb];
            short8 bl = *(const short8*)&Bl[(nt * 16 + ln) * 136 + kb];
#pragma unroll
            for (int mh = 0; mh < 2; mh++) {
                acc[mh][nt] = __builtin_amdgcn_mfma_f32_16x16x32_bf16(ahi[mh], bh, acc[mh][nt], 0, 0, 0);
                acc[mh][nt] = __builtin_amdgcn_mfma_f32_16x16x32_bf16(alo[mh], bh, acc[mh][nt], 0, 0, 0);
                acc[mh][nt] = __builtin_amdgcn_mfma_f32_16x16x32_bf16(ahi[mh], bl, acc[mh][nt], 0, 0, 0);
            }
        }
    }
#pragma unroll
    for (int mh = 0; mh < 2; mh++)
#pragma unroll
        for (int nt = 0; nt < 8; nt++) {
            float bv = bias[nt * 16 + ln];
#pragma unroll
            for (int r = 0; r < 4; r++) {
                int row = rW + mh * 16 + quad * 4 + r;
                if (row < NN) Y[(size_t)row * CC + nt * 16 + ln] = acc[mh][nt][r] + bv;
            }
        }
}

// ===========================================================================
// Semantic-attention column sums via split-bf16 MFMA (obuf already relu'd)
// ===========================================================================
__global__ __launch_bounds__(256) void semcol_mfma(
    const float* __restrict__ Obase,
    const unsigned short* __restrict__ whi, const unsigned short* __restrict__ wlo,
    const float* __restrict__ Kb, float* __restrict__ colsum)
{
    const int s = blockIdx.y;
    const float* X = Obase + (size_t)s * NC;

    __shared__ unsigned short Bh[128 * 136];
    __shared__ unsigned short Bl[128 * 136];
    __shared__ float red[4 * 128];
    const int tid = threadIdx.x;
    for (int i = tid; i < 128 * 16; i += 256) {
        int n = i >> 4, ch = (i & 15) * 8;
        *(short8*)&Bh[n * 136 + ch] = *(const short8*)&whi[n * 128 + ch];
        *(short8*)&Bl[n * 136 + ch] = *(const short8*)&wlo[n * 128 + ch];
    }
    __syncthreads();

    const int wave = tid >> 6, lane = tid & 63;
    const int ln = lane & 15, quad = lane >> 4;
    const int rW = blockIdx.x * 128 + wave * 32;

    floatx4 acc[2][8];
#pragma unroll
    for (int mh = 0; mh < 2; mh++)
#pragma unroll
        for (int nt = 0; nt < 8; nt++) acc[mh][nt] = (floatx4){0.f, 0.f, 0.f, 0.f};

    for (int ki = 0; ki < 4; ki++) {
        short8 ahi[2], alo[2];
#pragma unroll
        for (int mh = 0; mh < 2; mh++) {
            int row = rW + mh * 16 + ln; if (row > NN - 1) row = NN - 1;
            const float* ap = X + (size_t)row * CC + ki * 32 + quad * 8;
            float4 a0 = *(const float4*)ap;
            float4 a1 = *(const float4*)(ap + 4);
            float av[8] = {a0.x, a0.y, a0.z, a0.w, a1.x, a1.y, a1.z, a1.w};
#pragma unroll
            for (int j = 0; j < 8; j++) {
                unsigned short h = bf16_trunc(av[j]);
                float fh = __uint_as_float((unsigned)h << 16);
                ahi[mh][j] = (short)h;
                alo[mh][j] = (short)bf16_trunc(av[j] - fh);
            }
        }
        const int kb = ki * 32 + quad * 8;
#pragma unroll
        for (int nt = 0; nt < 8; nt++) {
            short8 bh = *(const short8*)&Bh[(nt * 16 + ln) * 136 + kb];
            short8 bl = *(const short8*)&Bl[(nt * 16 + ln) * 136 + kb];
#pragma unroll
            for (int mh = 0; mh < 2; mh++) {
                acc[mh][nt] = __builtin_amdgcn_mfma_f32_16x16x32_bf16(ahi[mh], bh, acc[mh][nt], 0, 0, 0);
                acc[mh][nt] = __builtin_amdgcn_mfma_f32_16x16x32_bf16(alo[mh], bh, acc[mh][nt], 0, 0, 0);
                acc[mh][nt] = __builtin_amdgcn_mfma_f32_16x16x32_bf16(ahi[mh], bl, acc[mh][nt], 0, 0, 0);
            }
        }
    }
    float tsum[8];
#pragma unroll
    for (int nt = 0; nt < 8; nt++) {
        float bv = Kb[nt * 16 + ln];
        float v = 0.f;
#pragma unroll
        for (int mh = 0; mh < 2; mh++)
#pragma unroll
            for (int r = 0; r < 4; r++) {
                int row = rW + mh * 16 + quad * 4 + r;
                if (row < NN) v += tanhf(acc[mh][nt][r] + bv);
            }
        v += __shfl_xor(v, 16);
        v += __shfl_xor(v, 32);
        tsum[nt] = v;
    }
    if (quad == 0) {
#pragma unroll
        for (int nt = 0; nt < 8; nt++) red[wave * 128 + nt * 16 + ln] = tsum[nt];
    }
    __syncthreads();
    if (tid < 128) {
        float v = red[tid] + red[128 + tid] + red[256 + tid] + red[384 + tid];
        unsafeAtomicAdd(&colsum[s * CC + tid], v);
    }
}

// ===========================================================================
// All 4 edge types' attention logits; block 0 also zero-inits colsum.
// ===========================================================================
__global__ __launch_bounds__(256) void al_all(
    const float* __restrict__ h0, const float* __restrict__ h1,
    const float* __restrict__ asrc, const float* __restrict__ adst,
    float* __restrict__ als4, float* __restrict__ ald4,
    float* __restrict__ colsum)
{
    if (blockIdx.x == 0) {
        colsum[threadIdx.x] = 0.f;
        colsum[256 + threadIdx.x] = 0.f;
    }
    const int idx = blockIdx.x * 256 + threadIdx.x;
    if (idx >= NHt) return;
    const int n = idx >> 3, h = idx & 7;
    float r0[16], r1[16];
    const float* p0 = h0 + (size_t)n * CC + h * DD;
    const float* p1 = h1 + (size_t)n * CC + h * DD;
#pragma unroll
    for (int d = 0; d < 16; d += 4) {
        *(float4*)&r0[d] = *(const float4*)&p0[d];
        *(float4*)&r1[d] = *(const float4*)&p1[d];
    }
    const int est[4] = {0, 0, 1, 1}, edt[4] = {0, 1, 0, 1};
#pragma unroll
    for (int e = 0; e < 4; e++) {
        const float* av = asrc + (size_t)(e * HH + h) * DD;
        const float* bv = adst + (size_t)(e * HH + h) * DD;
        const float* hs = est[e] ? r1 : r0;
        const float* hd = edt[e] ? r1 : r0;
        float s1 = 0.f, s2 = 0.f;
#pragma unroll
        for (int d = 0; d < 16; d++) {
            s1 = fmaf(hs[d], av[d], s1);
            s2 = fmaf(hd[d], bv[d], s2);
        }
        als4[e * NHt + idx] = s1;
        ald4[e * NHt + idx] = s2;
    }
}

// ===========================================================================
// Fused edge softmax+aggregate, all 4 types in one dispatch (grid.y).
// Wave per dst; half-waves split edges; 8 gather rows in flight.
// ===========================================================================
__global__ __launch_bounds__(256) void edge_fused(
    const int* __restrict__ rowptr4, const int* __restrict__ srcs4,
    const float* __restrict__ als4, const float* __restrict__ ald4,
    const float* __restrict__ h0, const float* __restrict__ h1,
    float* __restrict__ obuf)
{
    const int y = blockIdx.y;
    const int* rowptr = rowptr4 + y * (NN + 1);
    const int* srcs = srcs4 + (size_t)y * NE;
    const float* als = als4 + (size_t)y * NHt;
    const float* ald = ald4 + (size_t)y * NHt;
    const float* hsrc = (y >= 2) ? h1 : h0;
    float* o = obuf + (size_t)(((y & 1) << 1) | (y >> 1)) * NC;

    const int dst = blockIdx.x * 4 + (threadIdx.x >> 6);
    const int lane = threadIdx.x & 63;
    const int half = lane >> 5;
    const int l32 = lane & 31;
    const int h = l32 >> 2;
    const float aldv = ald[dst * 8 + h];
    const int p1 = rowptr[dst + 1];
    const size_t cofs = (size_t)l32 * 4;
    float4 acc = {0.f, 0.f, 0.f, 0.f};
    float zs = 0.f;
    int p = rowptr[dst] + half;

    while (p + 14 < p1) {
        int sv[8]; float av[8]; float4 xv[8];
#pragma unroll
        for (int j = 0; j < 8; j++) sv[j] = srcs[p + 2 * j];
#pragma unroll
        for (int j = 0; j < 8; j++) {
            av[j] = als[sv[j] * 8 + h];
            xv[j] = *(const float4*)&hsrc[(size_t)sv[j] * CC + cofs];
        }
#pragma unroll
        for (int j = 0; j < 8; j++) {
            float sc = av[j] + aldv;
            sc = sc > 0.f ? sc : 0.2f * sc;
            const float e_ = __expf(sc);
            zs += e_;
            acc.x = fmaf(e_, xv[j].x, acc.x);
            acc.y = fmaf(e_, xv[j].y, acc.y);
            acc.z = fmaf(e_, xv[j].z, acc.z);
            acc.w = fmaf(e_, xv[j].w, acc.w);
        }
        p += 16;
    }
    for (; p < p1; p += 2) {
        const int s0 = srcs[p];
        float sc = als[s0 * 8 + h] + aldv;
        sc = sc > 0.f ? sc : 0.2f * sc;
        const float e_ = __expf(sc);
        zs += e_;
        const float4 xv_ = *(const float4*)&hsrc[(size_t)s0 * CC + cofs];
        acc.x = fmaf(e_, xv_.x, acc.x);
        acc.y = fmaf(e_, xv_.y, acc.y);
        acc.z = fmaf(e_, xv_.z, acc.z);
        acc.w = fmaf(e_, xv_.w, acc.w);
    }

    acc.x += __shfl_xor(acc.x, 32);
    acc.y += __shfl_xor(acc.y, 32);
    acc.z += __shfl_xor(acc.z, 32);
    acc.w += __shfl_xor(acc.w, 32);
    zs    += __shfl_xor(zs, 32);
    if (half == 0) {
        const float zinv = zs > 0.f ? 1.f / zs : 0.f;
        float4 outv = {fmaxf(acc.x * zinv, 0.f), fmaxf(acc.y * zinv, 0.f),
                       fmaxf(acc.z * zinv, 0.f), fmaxf(acc.w * zinv, 0.f)};
        *(float4*)&o[(size_t)dst * CC + cofs] = outv;
    }
}

// ===========================================================================
// Semantic softmax weights
// ===========================================================================
__global__ __launch_bounds__(128) void attn_kernel(
    const float* __restrict__ colsum, const float* __restrict__ q,
    float* __restrict__ attn)
{
    const int tid = threadIdx.x;
    const float qc = q[tid];
    __shared__ float part[2][4];
    float p[4];
#pragma unroll
    for (int s = 0; s < 4; s++) {
        float v = qc * colsum[s * CC + tid];
        for (int off = 32; off > 0; off >>= 1) v += __shfl_down(v, off);
        p[s] = v;
    }
    if ((tid & 63) == 0) {
        int w = tid >> 6;
#pragma unroll
        for (int s = 0; s < 4; s++) part[w][s] = p[s];
    }
    __syncthreads();
    if (tid == 0) {
        float sc[4];
#pragma unroll
        for (int s = 0; s < 4; s++) sc[s] = (part[0][s] + part[1][s]) / (float)NN;
#pragma unroll
        for (int t = 0; t < 2; t++) {
            float m = fmaxf(sc[2 * t], sc[2 * t + 1]);
            float e0 = expf(sc[2 * t] - m), e1 = expf(sc[2 * t + 1] - m);
            float inv = 1.f / (e0 + e1);
            attn[2 * t] = e0 * inv;
            attn[2 * t + 1] = e1 * inv;
        }
    }
}

// Final combine (only needed before pooling)
__global__ __launch_bounds__(256) void combine_kernel(
    const float* __restrict__ o, const float* __restrict__ attn,
    float* __restrict__ x0, float* __restrict__ x1)
{
    const int i = blockIdx.x * 256 + threadIdx.x;
    if (i >= NC) return;
    const float a0 = attn[0], a1 = attn[1], a2 = attn[2], a3 = attn[3];
    x0[i] = a0 * o[i] + a1 * o[(size_t)NC + i];
    x1[i] = a2 * o[2 * (size_t)NC + i] + a3 * o[3 * (size_t)NC + i];
}

// ===========================================================================
// Pooling + head
// ===========================================================================
__global__ __launch_bounds__(256) void pool_kernel(
    const float* __restrict__ x0, const float* __restrict__ x1,
    const int* __restrict__ b0, const int* __restrict__ b1,
    float* __restrict__ fmaxb, float* __restrict__ fsumb)
{
    const int t = blockIdx.y;
    const float* x = t ? x1 : x0;
    const int* batch = t ? b1 : b0;
    const int i = blockIdx.x * 256 + threadIdx.x;
    if (i >= (NN / 8) * CC) return;
    const int g = i >> 7, c = i & 127;
    const int n0 = g * 8;
    int curb = batch[n0];
    float vmax = 0.f, vsum = 0.f;
    for (int k = 0; k < 8; k++) {
        int n = n0 + k;
        int b = batch[n];
        float v = x[(size_t)n * CC + c];
        if (b != curb) {
            atomicMax((unsigned*)&fmaxb[(t * BBg + curb) * CC + c], __float_as_uint(vmax));
            unsafeAtomicAdd(&fsumb[(t * BBg + curb) * CC + c], vsum);
            curb = b; vmax = 0.f; vsum = 0.f;
        }
        vmax = fmaxf(vmax, v);
        vsum += v;
    }
    atomicMax((unsigned*)&fmaxb[(t * BBg + curb) * CC + c], __float_as_uint(vmax));
    unsafeAtomicAdd(&fsumb[(t * BBg + curb) * CC + c], vsum);
}

__global__ void cnt_kernel(const int* __restrict__ b0, const int* __restrict__ b1,
                           float* __restrict__ cnt)
{
    const int tid = threadIdx.x;
    if (tid >= 2 * BBg) return;
    const int* batch = (tid >= BBg) ? b1 : b0;
    const int b = tid & (BBg - 1);
    int lo0 = 0, hi0 = NN;
    while (lo0 < hi0) { int mid = (lo0 + hi0) >> 1; if (batch[mid] < b) lo0 = mid + 1; else hi0 = mid; }
    int lo1 = lo0, hi1 = NN;
    while (lo1 < hi1) { int mid = (lo1 + hi1) >> 1; if (batch[mid] < b + 1) lo1 = mid + 1; else hi1 = mid; }
    cnt[tid] = (float)(lo1 - lo0);
}

__global__ __launch_bounds__(512) void head_kernel(
    const float* __restrict__ fmaxb, const float* __restrict__ fsumb,
    const float* __restrict__ cnt,
    const float* __restrict__ W1, const float* __restrict__ bb1,
    const float* __restrict__ W2, const float* __restrict__ bb2,
    const float* __restrict__ W3, const float* __restrict__ bb3,
    float* __restrict__ out)
{
    __shared__ float F[32][512];
    __shared__ float scale[32];
    __shared__ float H1s[32][128];
    __shared__ float H2s[32][64];
    const int tid = threadIdx.x;
    const int j = tid;
    const int tt = j >> 8;
    const int jj = j & 255;
    const bool ismax = jj < 128;
    const int c = jj & 127;
    float csum = 0.f;
    for (int b = 0; b < 32; b++) {
        float v;
        if (ismax) v = fmaxb[(tt * BBg + b) * CC + c];
        else       v = fsumb[(tt * BBg + b) * CC + c] / fmaxf(cnt[tt * BBg + b], 1.f);
        F[b][j] = v;
        csum += v;
    }
    const float cmean = csum * (1.f / 32.f);
    for (int b = 0; b < 32; b++) F[b][j] -= cmean;
    __syncthreads();
    {
        const int b = tid >> 4, l = tid & 15;
        float s = 0.f;
        for (int jx = l; jx < 512; jx += 16) { float v = F[b][jx]; s += v * v; }
        for (int off = 8; off > 0; off >>= 1) s += __shfl_down(s, off);
        if (l == 0) scale[b] = 100.f / sqrtf(1e-6f + s);
    }
    __syncthreads();
    for (int b = 0; b < 32; b++) F[b][j] *= scale[b];
    __syncthreads();
    {
        const int co = tid & 127, bg = tid >> 7;
        float acc[8] = {};
        for (int k = 0; k < 512; k++) {
            float w = W1[k * 128 + co];
#pragma unroll
            for (int r = 0; r < 8; r++) acc[r] = fmaf(F[bg * 8 + r][k], w, acc[r]);
        }
        float bv = bb1[co];
#pragma unroll
        for (int r = 0; r < 8; r++) H1s[bg * 8 + r][co] = fmaxf(acc[r] + bv, 0.f);
    }
    __syncthreads();
    {
        const int co = tid & 63, bg = tid >> 6;
        float acc[4] = {};
        for (int k = 0; k < 128; k++) {
            float w = W2[k * 64 + co];
#pragma unroll
            for (int r = 0; r < 4; r++) acc[r] = fmaf(H1s[bg * 4 + r][k], w, acc[r]);
        }
        float bv = bb2[co];
#pragma unroll
        for (int r = 0; r < 4; r++) H2s[bg * 4 + r][co] = fmaxf(acc[r] + bv, 0.f);
    }
    __syncthreads();
    if (tid < 64) {
        const int b = tid >> 1, oc = tid & 1;
        float acc = bb3[oc];
        for (int k = 0; k < 64; k++) acc = fmaf(H2s[b][k], W3[k * 2 + oc], acc);
        out[b * 2 + oc] = acc;
    }
}

// ===========================================================================
extern "C" void kernel_launch(void* const* d_in, const int* in_sizes, int n_in,
                              void* d_out, int out_size, void* d_ws, size_t ws_size,
                              hipStream_t stream)
{
    const float* x_bold = (const float*)d_in[0];
    const float* x_dti  = (const float*)d_in[1];
    const float* proj_w = (const float*)d_in[2];
    const float* proj_b = (const float*)d_in[3];
    const float* a_src  = (const float*)d_in[4];
    const float* a_dst  = (const float*)d_in[5];
    const float* k_w    = (const float*)d_in[6];
    const float* k_b    = (const float*)d_in[7];
    const float* qv     = (const float*)d_in[8];
    const float* lin1_w = (const float*)d_in[9];
    const float* lin1_b = (const float*)d_in[10];
    const float* lin2_w = (const float*)d_in[11];
    const float* lin2_b = (const float*)d_in[12];
    const float* lin3_w = (const float*)d_in[13];
    const float* lin3_b = (const float*)d_in[14];
    const int* ei0 = (const int*)d_in[15];
    const int* ei1 = (const int*)d_in[16];
    const int* ei2 = (const int*)d_in[17];
    const int* ei3 = (const int*)d_in[18];
    const int* batch_bold = (const int*)d_in[19];
    const int* batch_dti  = (const int*)d_in[20];

    float* ws = (float*)d_ws;
    float* h0   = ws;                       // [N,C]
    float* h1   = h0 + NC;                  // [N,C]
    float* obuf = h1 + NC;                  // 4x[N,C]: {t0s0, t0s1, t1s0, t1s1}
    float* x0   = obuf + 4 * (size_t)NC;    // [N,C] (final combine only)
    float* x1   = x0 + NC;                  // [N,C]
    float* als4 = x1 + NC;                  // [4][N,H]
    float* ald4 = als4 + 4 * (size_t)NHt;   // [4][N,H]
    float* colsum = ald4 + 4 * (size_t)NHt; // [4,C]
    float* attn   = colsum + 4 * CC;        // [4]
    float* fmaxb  = attn + 4;               // [2,B,C]
    float* fsumb  = fmaxb + 2 * BBg * CC;   // [2,B,C]
    float* cnt    = fsumb + 2 * BBg * CC;   // [2,B]
    char* pc = (char*)(cnt + 2 * BBg);
    pc = (char*)(((uintptr_t)pc + 15) & ~(uintptr_t)15);
    unsigned short* wt_hi = (unsigned short*)pc;     // [9][128][128] bf16 transposed
    unsigned short* wt_lo = wt_hi + 9 * 16384;
    int* deg4    = (int*)(wt_lo + 9 * 16384);        // [4][N]
    int* cursor4 = deg4 + 4 * NN;                    // [4][N]
    int* rowptr4 = cursor4 + 4 * NN;                 // [4][N+1]
    int* srcs4   = rowptr4 + 4 * (NN + 1);           // [4][E]

    // ---- CSR build (windowed) + weight prep ----
    hipMemsetAsync(deg4, 0, 4 * NN * sizeof(int), stream);
    hist_all<<<dim3((NE + 255) / 256, 4), 256, 0, stream>>>(ei0, ei1, ei2, ei3, deg4);
    scan_all<<<4, 1024, 0, stream>>>(deg4, rowptr4, cursor4);
    scatter_all<<<dim3((NE + 255) / 256, 4), 256, 0, stream>>>(ei0, ei1, ei2, ei3,
                                                               cursor4, srcs4);
    wprep_kernel<<<(9 * 16384 + 255) / 256, 256, 0, stream>>>(proj_w, k_w, wt_hi, wt_lo);

    for (int l = 0; l < 3; l++) {
        if (l == 0) {
            proj_mfma<<<dim3(157, 2), 256, 0, stream>>>(
                x_bold, x_bold, x_dti, x_dti, nullptr,
                wt_hi, wt_lo, proj_b, h0, h1);
        } else {
            proj_mfma<<<dim3(157, 2), 256, 0, stream>>>(
                obuf, obuf + NC, obuf + 2 * (size_t)NC, obuf + 3 * (size_t)NC, attn,
                wt_hi + (size_t)l * 2 * 16384, wt_lo + (size_t)l * 2 * 16384,
                proj_b + (size_t)l * 2 * CC, h0, h1);
        }
        al_all<<<625, 256, 0, stream>>>(
            h0, h1, a_src + (size_t)l * 4 * HH * DD, a_dst + (size_t)l * 4 * HH * DD,
            als4, ald4, colsum);
        edge_fused<<<dim3(NN / 4, 4), 256, 0, stream>>>(
            rowptr4, srcs4, als4, ald4, h0, h1, obuf);
        semcol_mfma<<<dim3(157, 4), 256, 0, stream>>>(
            obuf, wt_hi + (size_t)(6 + l) * 16384, wt_lo + (size_t)(6 + l) * 16384,
            k_b + (size_t)l * CC, colsum);
        attn_kernel<<<1, 128, 0, stream>>>(colsum, qv + l * CC, attn);
    }

    combine_kernel<<<(NC + 255) / 256, 256, 0, stream>>>(obuf, attn, x0, x1);
    hipMemsetAsync(fmaxb, 0, 2 * 2 * BBg * CC * sizeof(float), stream);
    pool_kernel<<<dim3((NN / 8) * CC / 256, 2), 256, 0, stream>>>(
        x0, x1, batch_bold, batch_dti, fmaxb, fsumb);
    cnt_kernel<<<1, 64, 0, stream>>>(batch_bold, batch_dti, cnt);
    head_kernel<<<1, 512, 0, stream>>>(fmaxb, fsumb, cnt, lin1_w, lin1_b,
                                       lin2_w, lin2_b, lin3_w, lin3_b, (float*)d_out);
}